// Round 1
// baseline (107509.375 us; speedup 1.0000x reference)
//
#include <hip/hip_runtime.h>
#include <math.h>

// LSTMNN: T=1024, B=64, I=128, H=512, L=2, fp32.
// Persistent-kernel design (round 1, fp32 correctness baseline):
//   256 WGs x 256 thr. WG k owns h-columns {2k,2k+1} of BOTH layers.
//   Step t: phase B = [out(t-1)] + layer-0 gates/cell; grid barrier;
//           phase C = layer-1 gates/cell + [inp(t+1)]; grid barrier.
//   Activations stored K-major ([feat][batch]) in ws, parity double-buffered.
//   Custom 2-level grid barrier (agent-scope atomics) in ws.
//   LDS: 32KB weight stage + 2x16KB act chunks (64KB total, static-safe).

namespace {

constexpr int T_STEPS = 1024;
constexpr int B = 64;
constexpr int I_DIM = 128;
constexpr int H = 512;
constexpr int NBLK = 256;
constexpr int NTHR = 256;

// ws layout in floats
constexpr int OFF_INPT = 0;                  // [512][64] inp^T(t)
constexpr int OFF_H0B  = OFF_INPT + H * B;   // [2][512][64] h0^T parity buffers
constexpr int OFF_H0C  = OFF_H0B + 2 * H * B;// [512][64] h0^T(t) for phase C
constexpr int OFF_H1C  = OFF_H0C + H * B;    // [2][512][64] h1^T parity buffers
constexpr int OFF_BSUM = OFF_H1C + 2 * H * B;// [2][2048] b_ih+b_hh
constexpr int OFF_BAR  = OFF_BSUM + 2 * 4 * H; // 32 uints barrier state
}  // namespace

__global__ __launch_bounds__(NTHR) void init_ws_kernel(
    float* __restrict__ ws, const float* __restrict__ b_ih,
    const float* __restrict__ b_hh) {
  int idx = blockIdx.x * blockDim.x + threadIdx.x;
  for (int f = idx; f < OFF_BSUM; f += NBLK * NTHR) ws[f] = 0.f;
  if (idx < 2 * 4 * H) ws[OFF_BSUM + idx] = b_ih[idx] + b_hh[idx];
  if (idx < 32) reinterpret_cast<unsigned*>(ws + OFF_BAR)[idx] = 0u;
}

__device__ __forceinline__ float sigm(float x) {
  return 1.f / (1.f + __expf(-x));
}
__device__ __forceinline__ float tanh_fast(float x) {
  float e = __expf(-2.f * fabsf(x));
  float t = (1.f - e) / (1.f + e);
  return x < 0.f ? -t : t;
}

__global__ __launch_bounds__(NTHR) void lstm_kernel(
    const float* __restrict__ x, const float* __restrict__ w_in,
    const float* __restrict__ b_in, const float* __restrict__ w_ih,
    const float* __restrict__ w_hh, const float* __restrict__ w_out,
    const float* __restrict__ b_out, float* __restrict__ ws,
    float* __restrict__ out) {
  __shared__ float s_w[8 * 1024];      // 32 KB: 8 gate rows x [w_ih(512)|w_hh(512)]
  __shared__ float s_act[2][64 * 64];  // 2 x 16 KB act chunks (64 k-rows x 64 b)
  float* const s_red = s_act[0];          // 2048-float reduction scratch (aliased)
  float* const s_g   = s_act[0] + 2048;   // 512-float gate buffer (aliased)

  const int tid = threadIdx.x;
  const int wg = blockIdx.x;
  unsigned* const bar = reinterpret_cast<unsigned*>(ws + OFF_BAR);

  // ---- grid barrier: 16 groups of 16 blocks + master, generation flag ----
  auto gridbar = [&]() {
    __syncthreads();
    if (tid == 0) {
      if (__hip_atomic_load(bar + 18, __ATOMIC_RELAXED,
                            __HIP_MEMORY_SCOPE_AGENT) == 0u) {
        __threadfence();
        unsigned gen = __hip_atomic_load(bar + 17, __ATOMIC_RELAXED,
                                         __HIP_MEMORY_SCOPE_AGENT);
        unsigned grp = (unsigned)wg & 15u;
        unsigned prev = __hip_atomic_fetch_add(bar + grp, 1u, __ATOMIC_ACQ_REL,
                                               __HIP_MEMORY_SCOPE_AGENT);
        bool done = false;
        if (prev == 15u) {
          __hip_atomic_store(bar + grp, 0u, __ATOMIC_RELAXED,
                             __HIP_MEMORY_SCOPE_AGENT);
          unsigned mprev = __hip_atomic_fetch_add(
              bar + 16, 1u, __ATOMIC_ACQ_REL, __HIP_MEMORY_SCOPE_AGENT);
          if (mprev == 15u) {
            __hip_atomic_store(bar + 16, 0u, __ATOMIC_RELAXED,
                               __HIP_MEMORY_SCOPE_AGENT);
            __hip_atomic_fetch_add(bar + 17, 1u, __ATOMIC_RELEASE,
                                   __HIP_MEMORY_SCOPE_AGENT);
            done = true;
          }
        }
        if (!done) {
          int spin = 0;
          while (__hip_atomic_load(bar + 17, __ATOMIC_ACQUIRE,
                                   __HIP_MEMORY_SCOPE_AGENT) == gen) {
            __builtin_amdgcn_s_sleep(2);
            if (++spin > (1 << 17)) {  // failsafe: fast-fail, don't hang
              __hip_atomic_store(bar + 18, 1u, __ATOMIC_RELAXED,
                                 __HIP_MEMORY_SCOPE_AGENT);
              break;
            }
          }
        }
        __threadfence();
      }
    }
    __syncthreads();
  };

  // ---- out(tt) = h1(tt) @ w_out^T + b_out; h1 from h1C[buf] ----
  auto out_block = [&](int tt, int buf) {
    const int o = tid & 31, ks = tid >> 5;
    const int b = wg >> 2;
    const int i = (wg & 3) * 32 + o;
    const float* hcol = ws + OFF_H1C + buf * (H * B) + (ks * 64) * 64 + b;
    const float* wrow = w_out + (size_t)i * H + ks * 64;
    float part = 0.f;
#pragma unroll
    for (int k4 = 0; k4 < 16; ++k4) {
      float4 wv = *reinterpret_cast<const float4*>(wrow + k4 * 4);
      part += wv.x * hcol[(k4 * 4 + 0) * 64] + wv.y * hcol[(k4 * 4 + 1) * 64] +
              wv.z * hcol[(k4 * 4 + 2) * 64] + wv.w * hcol[(k4 * 4 + 3) * 64];
    }
    s_red[tid] = part;
    __syncthreads();
    if (tid < 32) {
      float sum = 0.f;
#pragma unroll
      for (int kk = 0; kk < 8; ++kk) sum += s_red[kk * 32 + tid];
      int ii = (wg & 3) * 32 + tid;
      out[((size_t)tt * B + b) * I_DIM + ii] = sum + b_out[ii];
    }
    __syncthreads();
  };

  // ---- inp(tn) = sigmoid(x[tn] @ w_in^T + b_in) -> inp^T cols {2wg,2wg+1} ----
  auto inp_block = [&](int tn) {
    const int ks = tid >> 7, cc = (tid >> 6) & 1, b = tid & 63;
    const int col = wg * 2 + cc;
    const float* xsrc = x + ((size_t)tn * B + b) * I_DIM + ks * 64;
    const float* wrow = w_in + (size_t)col * I_DIM + ks * 64;
    float part = 0.f;
#pragma unroll
    for (int k4 = 0; k4 < 16; ++k4) {
      float4 xv = *reinterpret_cast<const float4*>(xsrc + k4 * 4);
      float4 wv = *reinterpret_cast<const float4*>(wrow + k4 * 4);
      part += xv.x * wv.x + xv.y * wv.y + xv.z * wv.z + xv.w * wv.w;
    }
    s_red[tid] = part;
    __syncthreads();
    if (tid < 128) {
      float v = s_red[tid] + s_red[tid + 128];
      ws[OFF_INPT + col * 64 + b] = sigm(v + b_in[col]);
    }
  };

  // ---- gates for layer: 8 rows x 64 b, K=1024 from [lo(512) ; hi(512)] ----
  // Result (pre-activation + bias) left in s_g[r*64+b].
  auto gemv = [&](const float* __restrict__ lo, const float* __restrict__ hi,
                  const int layer) {
    // stage this layer's 8 weight rows: s_w[R][k], k<512 = w_ih, k>=512 = w_hh
#pragma unroll
    for (int it = 0; it < 8; ++it) {
      int f4 = it * 256 + tid;
      int R = f4 >> 8;
      int k = (f4 & 255) * 4;
      int grow = (R >> 1) * 512 + wg * 2 + (R & 1);
      const float* srcp =
          (k < 512) ? (w_ih + ((size_t)layer * 4 * H + grow) * H + k)
                    : (w_hh + ((size_t)layer * 4 * H + grow) * H + (k - 512));
      *reinterpret_cast<float4*>(s_w + R * 1024 + k) =
          *reinterpret_cast<const float4*>(srcp);
    }
    // stage chunk 0 (rows [0,64) of lo)
#pragma unroll
    for (int v = 0; v < 4; ++v) {
      int f4 = v * 256 + tid;
      *reinterpret_cast<float4*>(&s_act[0][f4 * 4]) =
          *reinterpret_cast<const float4*>(lo + f4 * 4);
    }
    __syncthreads();

    const int s = tid >> 3;   // 0..31 k-slice
    const int tb = tid & 7;   // batch tile of 8
    const int kb = s * 2;     // k offset within 64-row chunk
    float acc[64];
#pragma unroll
    for (int q = 0; q < 64; ++q) acc[q] = 0.f;

#pragma unroll 2
    for (int c = 0; c < 16; ++c) {
      const float* cur = s_act[c & 1];
      float4 pre[4];
      const bool more = (c + 1 < 16);
      if (more) {
        const int cn = c + 1;
        const float* srcp = (cn < 8) ? (lo + cn * 4096) : (hi + (cn - 8) * 4096);
#pragma unroll
        for (int v = 0; v < 4; ++v)
          pre[v] = *reinterpret_cast<const float4*>(srcp + (v * 256 + tid) * 4);
      }
      float av[2][8];
#pragma unroll
      for (int j = 0; j < 2; ++j) {
        float4 p0 = *reinterpret_cast<const float4*>(cur + (kb + j) * 64 + tb * 8);
        float4 p1 =
            *reinterpret_cast<const float4*>(cur + (kb + j) * 64 + tb * 8 + 4);
        av[j][0] = p0.x; av[j][1] = p0.y; av[j][2] = p0.z; av[j][3] = p0.w;
        av[j][4] = p1.x; av[j][5] = p1.y; av[j][6] = p1.z; av[j][7] = p1.w;
      }
#pragma unroll
      for (int r = 0; r < 8; ++r) {
        float2 w2 =
            *reinterpret_cast<const float2*>(s_w + r * 1024 + c * 64 + kb);
#pragma unroll
        for (int bb = 0; bb < 8; ++bb) acc[r * 8 + bb] += w2.x * av[0][bb];
#pragma unroll
        for (int bb = 0; bb < 8; ++bb) acc[r * 8 + bb] += w2.y * av[1][bb];
      }
      if (more) {
        float* nxt = s_act[(c + 1) & 1];
#pragma unroll
        for (int v = 0; v < 4; ++v)
          *reinterpret_cast<float4*>(nxt + (v * 256 + tid) * 4) = pre[v];
      }
      __syncthreads();
    }

    // reduce k-slices: butterfly over lane bits 3..5 (s mod 8 within wave)
#pragma unroll
    for (int m = 8; m <= 32; m <<= 1)
#pragma unroll
      for (int q = 0; q < 64; ++q) acc[q] += __shfl_xor(acc[q], m, 64);
    const int wave = tid >> 6;
    if ((tid & 56) == 0) {
      float* dst = s_red + (wave * 8 + tb) * 64;
#pragma unroll
      for (int q = 0; q < 64; ++q) dst[q] = acc[q];
    }
    __syncthreads();
    // cross-wave sum + bias -> s_g
    const float* bsum_l = ws + OFF_BSUM + layer * 4 * H;
#pragma unroll
    for (int gp = 0; gp < 2; ++gp) {
      int G = tid + gp * 256;
      int r = G >> 6, b = G & 63;
      float sum = 0.f;
#pragma unroll
      for (int w = 0; w < 4; ++w)
        sum += s_red[(w * 8 + (b >> 3)) * 64 + r * 8 + (b & 7)];
      int grow = (r >> 1) * 512 + wg * 2 + (r & 1);
      s_g[r * 64 + b] = sum + bsum_l[grow];
    }
    __syncthreads();
  };

  float cs0 = 0.f, cs1 = 0.f;  // cell state: thread tid<128 owns (col=2wg+(tid>>6), b=tid&63)

  inp_block(0);
  gridbar();

  for (int t = 0; t < T_STEPS; ++t) {
    const int p = t & 1;
    // ---------------- phase B: out(t-1) + layer 0 ----------------
    if (t > 0) out_block(t - 1, p);
    gemv(ws + OFF_INPT, ws + OFF_H0B + p * (H * B), 0);
    if (tid < 128) {
      const int cc = tid >> 6, b = tid & 63, col = wg * 2 + cc;
      float gi = s_g[(0 + cc) * 64 + b];
      float gf = s_g[(2 + cc) * 64 + b];
      float gg = s_g[(4 + cc) * 64 + b];
      float go = s_g[(6 + cc) * 64 + b];
      float ig = sigm(gi), fg = sigm(gf), gt = tanh_fast(gg), og = sigm(go);
      cs0 = fg * cs0 + ig * gt;
      float h = og * tanh_fast(cs0);
      ws[OFF_H0C + col * 64 + b] = h;
      ws[OFF_H0B + (1 - p) * (H * B) + col * 64 + b] = h;
    }
    gridbar();
    // ---------------- phase C: layer 1 + inp(t+1) ----------------
    gemv(ws + OFF_H0C, ws + OFF_H1C + p * (H * B), 1);
    if (tid < 128) {
      const int cc = tid >> 6, b = tid & 63, col = wg * 2 + cc;
      float gi = s_g[(0 + cc) * 64 + b];
      float gf = s_g[(2 + cc) * 64 + b];
      float gg = s_g[(4 + cc) * 64 + b];
      float go = s_g[(6 + cc) * 64 + b];
      float ig = sigm(gi), fg = sigm(gf), gt = tanh_fast(gg), og = sigm(go);
      cs1 = fg * cs1 + ig * gt;
      float h = og * tanh_fast(cs1);
      ws[OFF_H1C + (1 - p) * (H * B) + col * 64 + b] = h;
    }
    if (t + 1 < T_STEPS) inp_block(t + 1);
    gridbar();
  }
  out_block(T_STEPS - 1, 0);
}

extern "C" void kernel_launch(void* const* d_in, const int* in_sizes, int n_in,
                              void* d_out, int out_size, void* d_ws,
                              size_t ws_size, hipStream_t stream) {
  const float* x     = (const float*)d_in[0];
  const float* w_in  = (const float*)d_in[1];
  const float* b_in  = (const float*)d_in[2];
  const float* w_ih  = (const float*)d_in[3];
  const float* w_hh  = (const float*)d_in[4];
  const float* b_ih  = (const float*)d_in[5];
  const float* b_hh  = (const float*)d_in[6];
  const float* w_out = (const float*)d_in[7];
  const float* b_out = (const float*)d_in[8];
  float* ws  = (float*)d_ws;
  float* outp = (float*)d_out;

  hipLaunchKernelGGL(init_ws_kernel, dim3(NBLK), dim3(NTHR), 0, stream, ws,
                     b_ih, b_hh);
  hipLaunchKernelGGL(lstm_kernel, dim3(NBLK), dim3(NTHR), 0, stream, x, w_in,
                     b_in, w_ih, w_hh, w_out, b_out, ws, outp);
}

// Round 2
// 61017.804 us; speedup vs baseline: 1.7619x; 1.7619x over previous
//
#include <hip/hip_runtime.h>
#include <math.h>

// LSTMNN: T=1024, B=64, I=128, H=512, L=2, fp32.
// Round 2: persistent kernel, 256 WGs x 512 thr (8 waves/CU).
//   - Acts read straight from ws (L2) into registers; NO act LDS staging
//     (round-1 counters: 3.1e9 LDS bank conflicts from act tiles).
//   - ONE grid barrier per step: span(t) = layer1(t) + out(t-1) +
//     layer0(t+1) + inp(t+2); parity double-buffers for inp/h0/h1.
//   - Weights staged per-gemv to LDS [8][1024] row-major (broadcast reads,
//     conflict-free); 50 KB static LDS total.

namespace {
constexpr int T_STEPS = 1024;
constexpr int B = 64;
constexpr int I_DIM = 128;
constexpr int H = 512;
constexpr int NBLK = 256;
constexpr int NTHR = 512;
constexpr int HB = H * B;  // 32768

// ws layout (floats)
constexpr int OFF_INP  = 0;               // [2][512][64] inp^T parity
constexpr int OFF_H0   = OFF_INP + 2 * HB;  // [2][512][64] h0^T parity
constexpr int OFF_H1   = OFF_H0 + 2 * HB;   // [2][512][64] h1^T parity
constexpr int OFF_BSUM = OFF_H1 + 2 * HB;   // [2][2048] b_ih+b_hh
constexpr int OFF_BAR  = OFF_BSUM + 2 * 4 * H;  // 32 uints barrier state
}  // namespace

__global__ __launch_bounds__(NTHR) void init_ws_kernel(
    float* __restrict__ ws, const float* __restrict__ b_ih,
    const float* __restrict__ b_hh) {
  int idx = blockIdx.x * blockDim.x + threadIdx.x;
  for (int f = idx; f < OFF_BSUM; f += NBLK * NTHR) ws[f] = 0.f;
  if (idx < 2 * 4 * H) ws[OFF_BSUM + idx] = b_ih[idx] + b_hh[idx];
  if (idx < 32) reinterpret_cast<unsigned*>(ws + OFF_BAR)[idx] = 0u;
}

__device__ __forceinline__ float sigm(float x) {
  return 1.f / (1.f + __expf(-x));
}
__device__ __forceinline__ float tanh_fast(float x) {
  float e = __expf(-2.f * fabsf(x));
  float t = (1.f - e) / (1.f + e);
  return x < 0.f ? -t : t;
}

__global__ __launch_bounds__(NTHR, 2) void lstm_kernel(
    const float* __restrict__ x, const float* __restrict__ w_in,
    const float* __restrict__ b_in, const float* __restrict__ w_ih,
    const float* __restrict__ w_hh, const float* __restrict__ w_out,
    const float* __restrict__ b_out, float* __restrict__ ws,
    float* __restrict__ out) {
  __shared__ float s_w[8 * 1024];  // 32 KB: current layer's 8 gate rows
  __shared__ float s_red[4096];    // 16 KB reduction scratch
  __shared__ float s_g[512];       // 2 KB gate pre-activations

  const int tid = threadIdx.x;
  const int wg = blockIdx.x;
  unsigned* const bar = reinterpret_cast<unsigned*>(ws + OFF_BAR);

  // ---- grid barrier: 16 groups of 16 blocks + master, generation flag ----
  auto gridbar = [&]() {
    __syncthreads();
    if (tid == 0) {
      if (__hip_atomic_load(bar + 18, __ATOMIC_RELAXED,
                            __HIP_MEMORY_SCOPE_AGENT) == 0u) {
        __threadfence();
        unsigned gen = __hip_atomic_load(bar + 17, __ATOMIC_RELAXED,
                                         __HIP_MEMORY_SCOPE_AGENT);
        unsigned grp = (unsigned)wg & 15u;
        unsigned prev = __hip_atomic_fetch_add(bar + grp, 1u, __ATOMIC_ACQ_REL,
                                               __HIP_MEMORY_SCOPE_AGENT);
        bool done = false;
        if (prev == 15u) {
          __hip_atomic_store(bar + grp, 0u, __ATOMIC_RELAXED,
                             __HIP_MEMORY_SCOPE_AGENT);
          unsigned mprev = __hip_atomic_fetch_add(
              bar + 16, 1u, __ATOMIC_ACQ_REL, __HIP_MEMORY_SCOPE_AGENT);
          if (mprev == 15u) {
            __hip_atomic_store(bar + 16, 0u, __ATOMIC_RELAXED,
                               __HIP_MEMORY_SCOPE_AGENT);
            __hip_atomic_fetch_add(bar + 17, 1u, __ATOMIC_RELEASE,
                                   __HIP_MEMORY_SCOPE_AGENT);
            done = true;
          }
        }
        if (!done) {
          int spin = 0;
          while (__hip_atomic_load(bar + 17, __ATOMIC_ACQUIRE,
                                   __HIP_MEMORY_SCOPE_AGENT) == gen) {
            __builtin_amdgcn_s_sleep(2);
            if (++spin > (1 << 17)) {  // failsafe: fast-fail, don't hang
              __hip_atomic_store(bar + 18, 1u, __ATOMIC_RELAXED,
                                 __HIP_MEMORY_SCOPE_AGENT);
              break;
            }
          }
        }
        __threadfence();
      }
    }
    __syncthreads();
  };

  // ---- out(tt) from h1^T parity buf (k-major; h reads broadcast over o) ----
  auto out_block = [&](int tt, int parb) {
    const int o = tid & 31, ks = tid >> 5;  // ks 0..15, 32 k each
    const int b = wg >> 2;
    const int i = (wg & 3) * 32 + o;
    const float* hcol = ws + OFF_H1 + parb * HB + (ks * 32) * 64 + b;
    const float* wrow = w_out + (size_t)i * H + ks * 32;
    float part = 0.f;
#pragma unroll
    for (int k4 = 0; k4 < 8; ++k4) {
      float4 wv = *reinterpret_cast<const float4*>(wrow + k4 * 4);
      part += wv.x * hcol[(k4 * 4 + 0) * 64] + wv.y * hcol[(k4 * 4 + 1) * 64] +
              wv.z * hcol[(k4 * 4 + 2) * 64] + wv.w * hcol[(k4 * 4 + 3) * 64];
    }
    s_red[tid] = part;
    __syncthreads();
    if (tid < 32) {
      float sum = 0.f;
#pragma unroll
      for (int kk = 0; kk < 16; ++kk) sum += s_red[kk * 32 + tid];
      int ii = (wg & 3) * 32 + tid;
      out[((size_t)tt * B + b) * I_DIM + ii] = sum + b_out[ii];
    }
    __syncthreads();
  };

  // ---- inp(tn) = sigmoid(x[tn] @ w_in^T + b_in) -> cols {2wg,2wg+1} ----
  auto inp_block = [&](int tn, int par) {
    const int b = tid & 63, cc = (tid >> 6) & 1, ks = tid >> 7;  // ks 0..3
    const int col = wg * 2 + cc;
    const float* xsrc = x + ((size_t)tn * B + b) * I_DIM + ks * 32;
    const float* wrow = w_in + (size_t)col * I_DIM + ks * 32;
    float part = 0.f;
#pragma unroll
    for (int k4 = 0; k4 < 8; ++k4) {
      float4 xv = *reinterpret_cast<const float4*>(xsrc + k4 * 4);
      float4 wv = *reinterpret_cast<const float4*>(wrow + k4 * 4);
      part += xv.x * wv.x + xv.y * wv.y + xv.z * wv.z + xv.w * wv.w;
    }
    s_red[tid] = part;
    __syncthreads();
    if (tid < 128) {
      float v = s_red[tid] + s_red[tid + 128] + s_red[tid + 256] +
                s_red[tid + 384];
      int col2 = wg * 2 + (tid >> 6), b2 = tid & 63;
      ws[OFF_INP + par * HB + col2 * 64 + b2] = sigm(v + b_in[col2]);
    }
    __syncthreads();
  };

  // ---- gates gemv: 8 rows x 64 b, K=1024 = [lo(512);hi(512)], k-major acts.
  // Stages weights to LDS, streams acts global->reg, leaves result in s_g.
  auto gemv = [&](const float* __restrict__ lo, const float* __restrict__ hi,
                  const int layer) {
    // stage weights row-major [8][1024]; coalesced global, conflict-free LDS
#pragma unroll
    for (int it = 0; it < 4; ++it) {
      int idx = it * 512 + tid;          // float4 index 0..2047
      int R = idx >> 8;                  // row 0..7
      int k = (idx & 255) * 4;           // float col 0..1023
      int grow = (R >> 1) * 512 + wg * 2 + (R & 1);
      const float* srcp =
          (k < 512) ? (w_ih + ((size_t)layer * 4 * H + grow) * H + k)
                    : (w_hh + ((size_t)layer * 4 * H + grow) * H + (k - 512));
      *reinterpret_cast<float4*>(s_w + R * 1024 + k) =
          *reinterpret_cast<const float4*>(srcp);
    }
    __syncthreads();

    const int s = tid >> 3;  // k-slice 0..63
    const int tb = tid & 7;  // batch octet
    const float* pl = lo + s * 64 + tb * 8;
    const float* ph = hi + s * 64 + tb * 8;
    float acc[64];
#pragma unroll
    for (int q = 0; q < 64; ++q) acc[q] = 0.f;

    float4 a0 = *reinterpret_cast<const float4*>(pl);
    float4 a1 = *reinterpret_cast<const float4*>(pl + 4);
#pragma unroll
    for (int c = 0; c < 16; ++c) {
      float4 n0, n1;
      if (c < 15) {  // register prefetch of next chunk's acts
        const float* np =
            (c + 1 < 8) ? (pl + (c + 1) * 4096) : (ph + (c + 1 - 8) * 4096);
        n0 = *reinterpret_cast<const float4*>(np);
        n1 = *reinterpret_cast<const float4*>(np + 4);
      }
      float w[8];
#pragma unroll
      for (int r = 0; r < 8; ++r) w[r] = s_w[r * 1024 + c * 64 + s];
      float av[8] = {a0.x, a0.y, a0.z, a0.w, a1.x, a1.y, a1.z, a1.w};
#pragma unroll
      for (int r = 0; r < 8; ++r)
#pragma unroll
        for (int bb = 0; bb < 8; ++bb) acc[r * 8 + bb] += w[r] * av[bb];
      a0 = n0;
      a1 = n1;
    }

    // in-wave butterfly over lane bits 3..5 (sums the 8 k-slices per wave)
#pragma unroll
    for (int m = 8; m <= 32; m <<= 1)
#pragma unroll
      for (int q = 0; q < 64; ++q) acc[q] += __shfl_xor(acc[q], m, 64);
    const int wv = tid >> 6;  // wave 0..7
    if ((tid & 56) == 0) {
      float* dst = s_red + (wv * 8 + tb) * 64;
#pragma unroll
      for (int q = 0; q < 64; ++q) dst[q] = acc[q];
    }
    __syncthreads();
    // final cross-wave sum + bias: one gate value per thread (512 = 8r x 64b)
    {
      const float* bsum_l = ws + OFF_BSUM + layer * 4 * H;
      int r = tid >> 6, b = tid & 63;
      float sum = 0.f;
#pragma unroll
      for (int w8 = 0; w8 < 8; ++w8)
        sum += s_red[(w8 * 8 + (b >> 3)) * 64 + r * 8 + (b & 7)];
      int grow = (r >> 1) * 512 + wg * 2 + (r & 1);
      s_g[r * 64 + b] = sum + bsum_l[grow];
    }
    __syncthreads();
  };

  float cs0 = 0.f, cs1 = 0.f;  // cell state: tid<128 owns (col=2wg+(tid>>6), b=tid&63)

  // cell update helper: reads s_g, updates cs, writes h^T into dst
  auto cell0_update = [&](float* dst) {
    if (tid < 128) {
      const int cc = tid >> 6, b = tid & 63, col = wg * 2 + cc;
      float ig = sigm(s_g[(0 + cc) * 64 + b]);
      float fg = sigm(s_g[(2 + cc) * 64 + b]);
      float gt = tanh_fast(s_g[(4 + cc) * 64 + b]);
      float og = sigm(s_g[(6 + cc) * 64 + b]);
      cs0 = fg * cs0 + ig * gt;
      dst[col * 64 + b] = og * tanh_fast(cs0);
    }
  };
  auto cell1_update = [&](float* dst) {
    if (tid < 128) {
      const int cc = tid >> 6, b = tid & 63, col = wg * 2 + cc;
      float ig = sigm(s_g[(0 + cc) * 64 + b]);
      float fg = sigm(s_g[(2 + cc) * 64 + b]);
      float gt = tanh_fast(s_g[(4 + cc) * 64 + b]);
      float og = sigm(s_g[(6 + cc) * 64 + b]);
      cs1 = fg * cs1 + ig * gt;
      dst[col * 64 + b] = og * tanh_fast(cs1);
    }
  };

  // ---------------- prologue ----------------
  inp_block(0, 0);
  inp_block(1, 1);
  gridbar();
  // layer0(0): lo=inp(0) par0, hi=h0(-1)=par1 (zeros); write h0 par0
  gemv(ws + OFF_INP + 0 * HB, ws + OFF_H0 + 1 * HB, 0);
  cell0_update(ws + OFF_H0 + 0 * HB);
  gridbar();

  // ---------------- main loop: one barrier per step ----------------
  for (int t = 0; t < T_STEPS; ++t) {
    const int p = t & 1;
    // layer1(t): lo=h0(t) par p, hi=h1(t-1) par 1-p; write h1 par p
    gemv(ws + OFF_H0 + p * HB, ws + OFF_H1 + (1 - p) * HB, 1);
    cell1_update(ws + OFF_H1 + p * HB);
    // out(t-1): reads h1(t-1) par 1-p
    if (t > 0) out_block(t - 1, 1 - p);
    // layer0(t+1): lo=inp(t+1) par 1-p, hi=h0(t) par p; write h0 par 1-p
    if (t + 1 < T_STEPS) {
      gemv(ws + OFF_INP + (1 - p) * HB, ws + OFF_H0 + p * HB, 0);
      cell0_update(ws + OFF_H0 + (1 - p) * HB);
    }
    // inp(t+2) -> par p
    if (t + 2 < T_STEPS) inp_block(t + 2, p);
    gridbar();
  }
  // epilogue: out(1023), h1 par 1
  out_block(T_STEPS - 1, 1);
}

extern "C" void kernel_launch(void* const* d_in, const int* in_sizes, int n_in,
                              void* d_out, int out_size, void* d_ws,
                              size_t ws_size, hipStream_t stream) {
  const float* x     = (const float*)d_in[0];
  const float* w_in  = (const float*)d_in[1];
  const float* b_in  = (const float*)d_in[2];
  const float* w_ih  = (const float*)d_in[3];
  const float* w_hh  = (const float*)d_in[4];
  const float* b_ih  = (const float*)d_in[5];
  const float* b_hh  = (const float*)d_in[6];
  const float* w_out = (const float*)d_in[7];
  const float* b_out = (const float*)d_in[8];
  float* ws   = (float*)d_ws;
  float* outp = (float*)d_out;

  hipLaunchKernelGGL(init_ws_kernel, dim3(NBLK), dim3(NTHR), 0, stream, ws,
                     b_ih, b_hh);
  hipLaunchKernelGGL(lstm_kernel, dim3(NBLK), dim3(NTHR), 0, stream, x, w_in,
                     b_in, w_ih, w_hh, w_out, b_out, ws, outp);
}

// Round 3
// 45669.391 us; speedup vs baseline: 2.3541x; 1.3361x over previous
//
#include <hip/hip_runtime.h>
#include <math.h>

// LSTMNN: T=1024, B=64, I=128, H=512, L=2, fp32.
// Round 3: persistent kernel, 256 WGs x 512 thr.
//   - FIX: grid-barrier polls are RELAXED (round-2's acquire-per-poll emitted
//     buffer_inv each iteration -> L2 invalidate storm, ~45us/barrier).
//     One release fence before arrival, one acquire fence after exit.
//   - Weights persistent in LDS (64KB data, stored transposed+padded
//     [layer][r][s][c pad 20] so gemv weight reads are conflict-free b128).
//   - Gemv: 4 groups of 4 chunks, acts register-prefetched one group ahead;
//     exchange-and-halve wave reduction (112 shfl vs 384 ops).
//   - One grid barrier per step (same schedule as round 2, which passed).

namespace {
constexpr int T_STEPS = 1024;
constexpr int B = 64;
constexpr int I_DIM = 128;
constexpr int H = 512;
constexpr int NBLK = 256;
constexpr int NTHR = 512;
constexpr int HB = H * B;  // 32768
constexpr int P = 20;      // padded chunk dim (16 chunks -> 20 slots)

// ws layout (floats)
constexpr int OFF_INP  = 0;                 // [2][512][64] inp^T parity
constexpr int OFF_H0   = OFF_INP + 2 * HB;  // [2][512][64] h0^T parity
constexpr int OFF_H1   = OFF_H0 + 2 * HB;   // [2][512][64] h1^T parity
constexpr int OFF_BSUM = OFF_H1 + 2 * HB;   // [2][2048] b_ih+b_hh
constexpr int OFF_BAR  = OFF_BSUM + 2 * 4 * H;  // 32 uints barrier state
}  // namespace

__global__ __launch_bounds__(NTHR) void init_ws_kernel(
    float* __restrict__ ws, const float* __restrict__ b_ih,
    const float* __restrict__ b_hh) {
  int idx = blockIdx.x * blockDim.x + threadIdx.x;
  for (int f = idx; f < OFF_BSUM; f += NBLK * NTHR) ws[f] = 0.f;
  if (idx < 2 * 4 * H) ws[OFF_BSUM + idx] = b_ih[idx] + b_hh[idx];
  if (idx < 32) reinterpret_cast<unsigned*>(ws + OFF_BAR)[idx] = 0u;
}

__device__ __forceinline__ float sigm(float x) {
  return 1.f / (1.f + __expf(-x));
}
__device__ __forceinline__ float tanh_fast(float x) {
  float e = __expf(-2.f * fabsf(x));
  float t = (1.f - e) / (1.f + e);
  return x < 0.f ? -t : t;
}

__global__ __launch_bounds__(NTHR, 2) void lstm_kernel(
    const float* __restrict__ x, const float* __restrict__ w_in,
    const float* __restrict__ b_in, const float* __restrict__ w_ih,
    const float* __restrict__ w_hh, const float* __restrict__ w_out,
    const float* __restrict__ b_out, float* __restrict__ ws,
    float* __restrict__ out) {
  __shared__ float s_w[2 * 8 * 64 * P];  // 80 KB persistent gate weights
  __shared__ float s_red[4096];          // 16 KB reduction scratch
  __shared__ float s_g[512];             // 2 KB gate pre-activations

  const int tid = threadIdx.x;
  const int wg = blockIdx.x;
  unsigned* const bar = reinterpret_cast<unsigned*>(ws + OFF_BAR);

  // ---- persistent weight load: s_w[((l*8+r)*64+s)*P + c] = W[l][grow][k],
  //      k = c*64 + s (K-concat: k<512 -> w_ih, else w_hh) ----
#pragma unroll
  for (int i = 0; i < 8; ++i) {
    int idx = i * 512 + tid;  // float4 unit 0..4095
    int l = idx >> 11;
    int rem = idx & 2047;
    int r = rem >> 8;
    int k0 = (rem & 255) * 4;
    int grow = (r >> 1) * 512 + wg * 2 + (r & 1);
    const float* srcp =
        (k0 < 512) ? (w_ih + ((size_t)l * 4 * H + grow) * H + k0)
                   : (w_hh + ((size_t)l * 4 * H + grow) * H + (k0 - 512));
    float4 v = *reinterpret_cast<const float4*>(srcp);
    float arr[4] = {v.x, v.y, v.z, v.w};
#pragma unroll
    for (int j = 0; j < 4; ++j) {
      int k = k0 + j;
      int c = k >> 6, ss = k & 63;
      s_w[((l * 8 + r) * 64 + ss) * P + c] = arr[j];
    }
  }
  __syncthreads();

  // ---- grid barrier: relaxed polls, single release/acquire fences ----
  auto gridbar = [&]() {
    __syncthreads();
    if (tid == 0) {
      if (__hip_atomic_load(bar + 18, __ATOMIC_RELAXED,
                            __HIP_MEMORY_SCOPE_AGENT) == 0u) {
        __threadfence();  // release: publish my writes before arrival
        unsigned gen = __hip_atomic_load(bar + 17, __ATOMIC_RELAXED,
                                         __HIP_MEMORY_SCOPE_AGENT);
        unsigned grp = (unsigned)wg & 15u;
        unsigned prev = __hip_atomic_fetch_add(bar + grp, 1u, __ATOMIC_RELAXED,
                                               __HIP_MEMORY_SCOPE_AGENT);
        bool done = false;
        if (prev == 15u) {
          __hip_atomic_store(bar + grp, 0u, __ATOMIC_RELAXED,
                             __HIP_MEMORY_SCOPE_AGENT);
          unsigned mprev = __hip_atomic_fetch_add(
              bar + 16, 1u, __ATOMIC_RELEASE, __HIP_MEMORY_SCOPE_AGENT);
          if (mprev == 15u) {
            __hip_atomic_store(bar + 16, 0u, __ATOMIC_RELAXED,
                               __HIP_MEMORY_SCOPE_AGENT);
            __hip_atomic_fetch_add(bar + 17, 1u, __ATOMIC_RELEASE,
                                   __HIP_MEMORY_SCOPE_AGENT);
            done = true;
          }
        }
        if (!done) {
          int spin = 0;
          while (__hip_atomic_load(bar + 17, __ATOMIC_RELAXED,
                                   __HIP_MEMORY_SCOPE_AGENT) == gen) {
            __builtin_amdgcn_s_sleep(4);
            if (++spin > (1 << 16)) {  // failsafe: fast-fail, don't hang
              __hip_atomic_store(bar + 18, 1u, __ATOMIC_RELAXED,
                                 __HIP_MEMORY_SCOPE_AGENT);
              break;
            }
          }
        }
        __threadfence();  // acquire: see peers' writes
      }
    }
    __syncthreads();
  };

  // ---- out(tt) from h1^T parity buf ----
  auto out_block = [&](int tt, int parb) {
    const int o = tid & 31, ks = tid >> 5;  // ks 0..15
    const int b = wg >> 2;
    const int i = (wg & 3) * 32 + o;
    const float* hcol = ws + OFF_H1 + parb * HB + (ks * 32) * 64 + b;
    const float* wrow = w_out + (size_t)i * H + ks * 32;
    float part = 0.f;
#pragma unroll
    for (int k4 = 0; k4 < 8; ++k4) {
      float4 wv = *reinterpret_cast<const float4*>(wrow + k4 * 4);
      part += wv.x * hcol[(k4 * 4 + 0) * 64] + wv.y * hcol[(k4 * 4 + 1) * 64] +
              wv.z * hcol[(k4 * 4 + 2) * 64] + wv.w * hcol[(k4 * 4 + 3) * 64];
    }
    s_red[tid] = part;
    __syncthreads();
    if (tid < 32) {
      float sum = 0.f;
#pragma unroll
      for (int kk = 0; kk < 16; ++kk) sum += s_red[kk * 32 + tid];
      int ii = (wg & 3) * 32 + tid;
      out[((size_t)tt * B + b) * I_DIM + ii] = sum + b_out[ii];
    }
    __syncthreads();
  };

  // ---- inp(tn) = sigmoid(x[tn] @ w_in^T + b_in) -> cols {2wg,2wg+1} ----
  auto inp_block = [&](int tn, int par) {
    const int b = tid & 63, cc = (tid >> 6) & 1, ks = tid >> 7;  // ks 0..3
    const int col = wg * 2 + cc;
    const float* xsrc = x + ((size_t)tn * B + b) * I_DIM + ks * 32;
    const float* wrow = w_in + (size_t)col * I_DIM + ks * 32;
    float part = 0.f;
#pragma unroll
    for (int k4 = 0; k4 < 8; ++k4) {
      float4 xv = *reinterpret_cast<const float4*>(xsrc + k4 * 4);
      float4 wv = *reinterpret_cast<const float4*>(wrow + k4 * 4);
      part += xv.x * wv.x + xv.y * wv.y + xv.z * wv.z + xv.w * wv.w;
    }
    s_red[tid] = part;
    __syncthreads();
    if (tid < 128) {
      float v = s_red[tid] + s_red[tid + 128] + s_red[tid + 256] +
                s_red[tid + 384];
      int col2 = wg * 2 + (tid >> 6), b2 = tid & 63;
      ws[OFF_INP + par * HB + col2 * 64 + b2] = sigm(v + b_in[col2]);
    }
    __syncthreads();
  };

  // ---- gates gemv: 8 rows x 64 b, K=1024 = [lo(512);hi(512)], k-major.
  // Weights from persistent LDS; acts streamed global->reg, group-prefetched.
  auto gemv = [&](const float* __restrict__ lo, const float* __restrict__ hi,
                  const int layer) {
    const int s = tid >> 3;  // k-slice 0..63
    const int tb = tid & 7;  // batch octet
    const int wbase = ((layer * 8) * 64 + s) * P;
    float acc[64];
#pragma unroll
    for (int q = 0; q < 64; ++q) acc[q] = 0.f;

    float4 a_cur[4][2], a_nxt[4][2];
#pragma unroll
    for (int c = 0; c < 4; ++c) {
      const float* p = lo + c * 4096 + s * 64 + tb * 8;
      a_cur[c][0] = *reinterpret_cast<const float4*>(p);
      a_cur[c][1] = *reinterpret_cast<const float4*>(p + 4);
    }
#pragma unroll
    for (int g = 0; g < 4; ++g) {
      if (g < 3) {
#pragma unroll
        for (int cc = 0; cc < 4; ++cc) {
          const int c = (g + 1) * 4 + cc;
          const float* p =
              (c < 8 ? lo + c * 4096 : hi + (c - 8) * 4096) + s * 64 + tb * 8;
          a_nxt[cc][0] = *reinterpret_cast<const float4*>(p);
          a_nxt[cc][1] = *reinterpret_cast<const float4*>(p + 4);
        }
      }
      float4 wr[8];
#pragma unroll
      for (int r = 0; r < 8; ++r)
        wr[r] = *reinterpret_cast<const float4*>(
            &s_w[wbase + r * (64 * P) + g * 4]);
#pragma unroll
      for (int cc = 0; cc < 4; ++cc) {
        float av[8] = {a_cur[cc][0].x, a_cur[cc][0].y, a_cur[cc][0].z,
                       a_cur[cc][0].w, a_cur[cc][1].x, a_cur[cc][1].y,
                       a_cur[cc][1].z, a_cur[cc][1].w};
#pragma unroll
        for (int r = 0; r < 8; ++r) {
          float w = (cc == 0) ? wr[r].x
                  : (cc == 1) ? wr[r].y
                  : (cc == 2) ? wr[r].z
                              : wr[r].w;
#pragma unroll
          for (int bb = 0; bb < 8; ++bb)
            acc[r * 8 + bb] = fmaf(w, av[bb], acc[r * 8 + bb]);
        }
      }
#pragma unroll
      for (int cc = 0; cc < 4; ++cc) {
        a_cur[cc][0] = a_nxt[cc][0];
        a_cur[cc][1] = a_nxt[cc][1];
      }
    }

    // ---- exchange-and-halve reduction over lane bits 3..5 ----
    const int lane = tid & 63;
    const bool b3 = (lane & 8) != 0;
    const bool b4 = (lane & 16) != 0;
    const bool b5 = (lane & 32) != 0;
    float v32[32];
#pragma unroll
    for (int go = 0; go < 4; ++go)
#pragma unroll
      for (int j = 0; j < 8; ++j) {
        float lc = acc[(2 * go + 0) * 8 + j];
        float hc = acc[(2 * go + 1) * 8 + j];
        float lo_o = __shfl_xor(lc, 8, 64);
        float hi_o = __shfl_xor(hc, 8, 64);
        v32[go * 8 + j] = b3 ? (hc + hi_o) : (lc + lo_o);
      }
    float v16[16];
#pragma unroll
    for (int go = 0; go < 2; ++go)
#pragma unroll
      for (int j = 0; j < 8; ++j) {
        float lc = v32[(2 * go + 0) * 8 + j];
        float hc = v32[(2 * go + 1) * 8 + j];
        float lo_o = __shfl_xor(lc, 16, 64);
        float hi_o = __shfl_xor(hc, 16, 64);
        v16[go * 8 + j] = b4 ? (hc + hi_o) : (lc + lo_o);
      }
    float fin[8];
#pragma unroll
    for (int j = 0; j < 8; ++j) {
      float lc = v16[j];
      float hc = v16[8 + j];
      float lo_o = __shfl_xor(lc, 32, 64);
      float hi_o = __shfl_xor(hc, 32, 64);
      fin[j] = b5 ? (hc + hi_o) : (lc + lo_o);
    }
    // lane holds (r=sigma, b=tb*8+j) summed over its wave's k-macro-slice
    const int wv = tid >> 6;
    const int sigma = (lane >> 3) & 7;
    float* dst = s_red + wv * 512 + sigma * 64 + tb * 8;
    *reinterpret_cast<float4*>(dst) = make_float4(fin[0], fin[1], fin[2], fin[3]);
    *reinterpret_cast<float4*>(dst + 4) =
        make_float4(fin[4], fin[5], fin[6], fin[7]);
    __syncthreads();
    {
      const float* bsum_l = ws + OFF_BSUM + layer * 4 * H;
      float sum = 0.f;
#pragma unroll
      for (int w8 = 0; w8 < 8; ++w8) sum += s_red[w8 * 512 + tid];
      int r = tid >> 6;
      int grow = (r >> 1) * 512 + wg * 2 + (r & 1);
      s_g[tid] = sum + bsum_l[grow];  // s_g[r*64+b]
    }
    __syncthreads();
  };

  float cs0 = 0.f, cs1 = 0.f;  // tid<128 owns (col=2wg+(tid>>6), b=tid&63)

  auto cell0_update = [&](float* dst) {
    if (tid < 128) {
      const int cc = tid >> 6, b = tid & 63, col = wg * 2 + cc;
      float ig = sigm(s_g[(0 + cc) * 64 + b]);
      float fg = sigm(s_g[(2 + cc) * 64 + b]);
      float gt = tanh_fast(s_g[(4 + cc) * 64 + b]);
      float og = sigm(s_g[(6 + cc) * 64 + b]);
      cs0 = fg * cs0 + ig * gt;
      dst[col * 64 + b] = og * tanh_fast(cs0);
    }
  };
  auto cell1_update = [&](float* dst) {
    if (tid < 128) {
      const int cc = tid >> 6, b = tid & 63, col = wg * 2 + cc;
      float ig = sigm(s_g[(0 + cc) * 64 + b]);
      float fg = sigm(s_g[(2 + cc) * 64 + b]);
      float gt = tanh_fast(s_g[(4 + cc) * 64 + b]);
      float og = sigm(s_g[(6 + cc) * 64 + b]);
      cs1 = fg * cs1 + ig * gt;
      dst[col * 64 + b] = og * tanh_fast(cs1);
    }
  };

  // ---------------- prologue ----------------
  inp_block(0, 0);
  inp_block(1, 1);
  gridbar();
  gemv(ws + OFF_INP + 0 * HB, ws + OFF_H0 + 1 * HB, 0);  // h0(-1)=par1 zeros
  cell0_update(ws + OFF_H0 + 0 * HB);
  gridbar();

  // ---------------- main loop: one barrier per step ----------------
  for (int t = 0; t < T_STEPS; ++t) {
    const int p = t & 1;
    gemv(ws + OFF_H0 + p * HB, ws + OFF_H1 + (1 - p) * HB, 1);
    cell1_update(ws + OFF_H1 + p * HB);
    if (t > 0) out_block(t - 1, 1 - p);
    if (t + 1 < T_STEPS) {
      gemv(ws + OFF_INP + (1 - p) * HB, ws + OFF_H0 + p * HB, 0);
      cell0_update(ws + OFF_H0 + (1 - p) * HB);
    }
    if (t + 2 < T_STEPS) inp_block(t + 2, p);
    gridbar();
  }
  out_block(T_STEPS - 1, 1);
}

extern "C" void kernel_launch(void* const* d_in, const int* in_sizes, int n_in,
                              void* d_out, int out_size, void* d_ws,
                              size_t ws_size, hipStream_t stream) {
  const float* x     = (const float*)d_in[0];
  const float* w_in  = (const float*)d_in[1];
  const float* b_in  = (const float*)d_in[2];
  const float* w_ih  = (const float*)d_in[3];
  const float* w_hh  = (const float*)d_in[4];
  const float* b_ih  = (const float*)d_in[5];
  const float* b_hh  = (const float*)d_in[6];
  const float* w_out = (const float*)d_in[7];
  const float* b_out = (const float*)d_in[8];
  float* ws   = (float*)d_ws;
  float* outp = (float*)d_out;

  hipLaunchKernelGGL(init_ws_kernel, dim3(NBLK), dim3(NTHR), 0, stream, ws,
                     b_ih, b_hh);
  hipLaunchKernelGGL(lstm_kernel, dim3(NBLK), dim3(NTHR), 0, stream, x, w_in,
                     b_in, w_ih, w_hh, w_out, b_out, ws, outp);
}

// Round 4
// 36476.300 us; speedup vs baseline: 2.9474x; 1.2520x over previous
//
#include <hip/hip_runtime.h>
#include <math.h>

// LSTMNN: T=1024, B=64, I=128, H=512, L=2, fp32.
// Round 4: persistent kernel, 256 WGs x 512 thr.
//   - REMOVED per-step __threadfence() pair (R3 counters: WRITE_SIZE 7x the
//     real act writes -> buffer_wbl2/buffer_inv full-L2 ops each step were
//     the ~30us/step stall). Cross-XCD coherence now via explicit sc0 sc1
//     flagged loads/stores (inline asm) on ALL inter-WG activation traffic;
//     barrier atomics provide ordering; vmcnt drain before s_barrier
//     publishes writes.
//   - h1 additionally stored batch-major (h1T) so out_block reads are
//     contiguous float4 sc-loads (issue-8-then-wait, one latency).
//   - s_sleep(1) barrier polls.
//   - Weights persistent in LDS (unchanged from R3).

namespace {
constexpr int T_STEPS = 1024;
constexpr int B = 64;
constexpr int I_DIM = 128;
constexpr int H = 512;
constexpr int NBLK = 256;
constexpr int NTHR = 512;
constexpr int HB = H * B;  // 32768
constexpr int P = 20;      // padded chunk dim for LDS weights

// ws layout (floats)
constexpr int OFF_INP  = 0;                  // [2][512][64] inp^T parity
constexpr int OFF_H0   = OFF_INP + 2 * HB;   // [2][512][64] h0^T parity
constexpr int OFF_H1   = OFF_H0 + 2 * HB;    // [2][512][64] h1^T parity (k-major)
constexpr int OFF_H1T  = OFF_H1 + 2 * HB;    // [2][64][512] h1 b-major parity
constexpr int OFF_BSUM = OFF_H1T + 2 * HB;   // [2][2048] b_ih+b_hh
constexpr int OFF_BAR  = OFF_BSUM + 2 * 4 * H;  // 32 uints barrier state
}  // namespace

typedef float f32x4 __attribute__((ext_vector_type(4)));

// issue two coherent (sc0 sc1: bypass L1/L2, read at coherence point) 16B
// loads WITHOUT waiting — pair with VMWAIT8 before use.
__device__ __forceinline__ void coh_issue2(const float* p, f32x4& a, f32x4& b) {
  asm volatile(
      "global_load_dwordx4 %0, %2, off sc0 sc1\n\t"
      "global_load_dwordx4 %1, %3, off sc0 sc1"
      : "=&v"(a), "=&v"(b)
      : "v"(p), "v"(p + 4)
      : "memory");
}

// wait for all outstanding vector-memory ops; tied operands force the
// dependency so uses can't be scheduled before the wait.
#define VMWAIT8(A, B, C, D, E, F, G, Hh)                                     \
  asm volatile("s_waitcnt vmcnt(0)"                                          \
               : "+v"(A), "+v"(B), "+v"(C), "+v"(D), "+v"(E), "+v"(F),       \
                 "+v"(G), "+v"(Hh))

__device__ __forceinline__ void coh_store1(float* p, float v) {
  asm volatile("global_store_dword %0, %1, off sc0 sc1" ::"v"(p), "v"(v)
               : "memory");
}

__global__ __launch_bounds__(NTHR) void init_ws_kernel(
    float* __restrict__ ws, const float* __restrict__ b_ih,
    const float* __restrict__ b_hh) {
  int idx = blockIdx.x * blockDim.x + threadIdx.x;
  for (int f = idx; f < OFF_BSUM; f += NBLK * NTHR) ws[f] = 0.f;
  if (idx < 2 * 4 * H) ws[OFF_BSUM + idx] = b_ih[idx] + b_hh[idx];
  if (idx < 32) reinterpret_cast<unsigned*>(ws + OFF_BAR)[idx] = 0u;
}

__device__ __forceinline__ float sigm(float x) {
  return 1.f / (1.f + __expf(-x));
}
__device__ __forceinline__ float tanh_fast(float x) {
  float e = __expf(-2.f * fabsf(x));
  float t = (1.f - e) / (1.f + e);
  return x < 0.f ? -t : t;
}

__global__ __launch_bounds__(NTHR, 2) void lstm_kernel(
    const float* __restrict__ x, const float* __restrict__ w_in,
    const float* __restrict__ b_in, const float* __restrict__ w_ih,
    const float* __restrict__ w_hh, const float* __restrict__ w_out,
    const float* __restrict__ b_out, float* __restrict__ ws,
    float* __restrict__ out) {
  __shared__ float s_w[2 * 8 * 64 * P];  // 80 KB persistent gate weights
  __shared__ float s_red[4096];          // 16 KB reduction scratch
  __shared__ float s_g[512];             // 2 KB gate pre-activations

  const int tid = threadIdx.x;
  const int wg = blockIdx.x;
  unsigned* const bar = reinterpret_cast<unsigned*>(ws + OFF_BAR);

  // ---- persistent weight load: s_w[((l*8+r)*64+s)*P + c] = W[l][grow][k],
  //      k = c*64 + s (K-concat: k<512 -> w_ih, else w_hh) ----
#pragma unroll
  for (int i = 0; i < 8; ++i) {
    int idx = i * 512 + tid;  // float4 unit 0..4095
    int l = idx >> 11;
    int rem = idx & 2047;
    int r = rem >> 8;
    int k0 = (rem & 255) * 4;
    int grow = (r >> 1) * 512 + wg * 2 + (r & 1);
    const float* srcp =
        (k0 < 512) ? (w_ih + ((size_t)l * 4 * H + grow) * H + k0)
                   : (w_hh + ((size_t)l * 4 * H + grow) * H + (k0 - 512));
    float4 v = *reinterpret_cast<const float4*>(srcp);
    float arr[4] = {v.x, v.y, v.z, v.w};
#pragma unroll
    for (int j = 0; j < 4; ++j) {
      int k = k0 + j;
      int c = k >> 6, ss = k & 63;
      s_w[((l * 8 + r) * 64 + ss) * P + c] = arr[j];
    }
  }
  __syncthreads();

  // ---- grid barrier: relaxed sc-atomics, NO cache-wide fences ----
  auto gridbar = [&]() {
    __syncthreads();  // all waves drain vmcnt before s_barrier -> writes
                      // (sc0 sc1 write-through) visible at coherence point
    if (tid == 0) {
      if (__hip_atomic_load(bar + 18, __ATOMIC_RELAXED,
                            __HIP_MEMORY_SCOPE_AGENT) == 0u) {
        unsigned gen = __hip_atomic_load(bar + 17, __ATOMIC_RELAXED,
                                         __HIP_MEMORY_SCOPE_AGENT);
        unsigned grp = (unsigned)wg & 15u;
        unsigned prev = __hip_atomic_fetch_add(bar + grp, 1u, __ATOMIC_RELAXED,
                                               __HIP_MEMORY_SCOPE_AGENT);
        bool done = false;
        if (prev == 15u) {
          __hip_atomic_store(bar + grp, 0u, __ATOMIC_RELAXED,
                             __HIP_MEMORY_SCOPE_AGENT);
          unsigned mprev = __hip_atomic_fetch_add(
              bar + 16, 1u, __ATOMIC_RELAXED, __HIP_MEMORY_SCOPE_AGENT);
          if (mprev == 15u) {
            __hip_atomic_store(bar + 16, 0u, __ATOMIC_RELAXED,
                               __HIP_MEMORY_SCOPE_AGENT);
            __hip_atomic_fetch_add(bar + 17, 1u, __ATOMIC_RELEASE,
                                   __HIP_MEMORY_SCOPE_AGENT);
            done = true;
          }
        }
        if (!done) {
          int spin = 0;
          while (__hip_atomic_load(bar + 17, __ATOMIC_RELAXED,
                                   __HIP_MEMORY_SCOPE_AGENT) == gen) {
            __builtin_amdgcn_s_sleep(1);
            if (++spin > (1 << 17)) {  // failsafe: fast-fail, don't hang
              __hip_atomic_store(bar + 18, 1u, __ATOMIC_RELAXED,
                                 __HIP_MEMORY_SCOPE_AGENT);
              break;
            }
          }
        }
      }
    }
    __syncthreads();
  };

  // ---- out(tt) from h1T (b-major) parity buf; contiguous sc-loads ----
  auto out_block = [&](int tt, int parb) {
    const int o = tid & 31, ks = tid >> 5;  // ks 0..15, 32 k each
    const int b = wg >> 2;
    const int i = (wg & 3) * 32 + o;
    const float* hrow = ws + OFF_H1T + parb * HB + b * 512 + ks * 32;
    const float* wrow = w_out + (size_t)i * H + ks * 32;
    f32x4 h0, h1, h2, h3, h4, h5, h6, h7;
    coh_issue2(hrow, h0, h1);
    coh_issue2(hrow + 8, h2, h3);
    coh_issue2(hrow + 16, h4, h5);
    coh_issue2(hrow + 24, h6, h7);
    VMWAIT8(h0, h1, h2, h3, h4, h5, h6, h7);
    f32x4 hq[8] = {h0, h1, h2, h3, h4, h5, h6, h7};
    float part = 0.f;
#pragma unroll
    for (int k4 = 0; k4 < 8; ++k4) {
      float4 wv = *reinterpret_cast<const float4*>(wrow + k4 * 4);
      part += wv.x * hq[k4].x + wv.y * hq[k4].y + wv.z * hq[k4].z +
              wv.w * hq[k4].w;
    }
    s_red[tid] = part;
    __syncthreads();
    if (tid < 32) {
      float sum = 0.f;
#pragma unroll
      for (int kk = 0; kk < 16; ++kk) sum += s_red[kk * 32 + tid];
      int ii = (wg & 3) * 32 + tid;
      out[((size_t)tt * B + b) * I_DIM + ii] = sum + b_out[ii];
    }
    __syncthreads();
  };

  // ---- inp(tn) = sigmoid(x[tn] @ w_in^T + b_in) -> cols {2wg,2wg+1} ----
  auto inp_block = [&](int tn, int par) {
    const int b = tid & 63, cc = (tid >> 6) & 1, ks = tid >> 7;  // ks 0..3
    const int col = wg * 2 + cc;
    const float* xsrc = x + ((size_t)tn * B + b) * I_DIM + ks * 32;
    const float* wrow = w_in + (size_t)col * I_DIM + ks * 32;
    float part = 0.f;
#pragma unroll
    for (int k4 = 0; k4 < 8; ++k4) {
      float4 xv = *reinterpret_cast<const float4*>(xsrc + k4 * 4);
      float4 wv = *reinterpret_cast<const float4*>(wrow + k4 * 4);
      part += xv.x * wv.x + xv.y * wv.y + xv.z * wv.z + xv.w * wv.w;
    }
    s_red[tid] = part;
    __syncthreads();
    if (tid < 128) {
      float v = s_red[tid] + s_red[tid + 128] + s_red[tid + 256] +
                s_red[tid + 384];
      int col2 = wg * 2 + (tid >> 6), b2 = tid & 63;
      coh_store1(ws + OFF_INP + par * HB + col2 * 64 + b2, sigm(v + b_in[col2]));
    }
    __syncthreads();
  };

  // ---- gates gemv: 8 rows x 64 b, K=1024 = [lo(512);hi(512)], k-major.
  // Weights from persistent LDS; acts via coherent issue/wait-split loads.
  auto gemv = [&](const float* __restrict__ lo, const float* __restrict__ hi,
                  const int layer) {
    const int s = tid >> 3;  // k-slice 0..63
    const int tb = tid & 7;  // batch octet
    const int wbase = ((layer * 8) * 64 + s) * P;
    float acc[64];
#pragma unroll
    for (int q = 0; q < 64; ++q) acc[q] = 0.f;

    f32x4 a_cur[4][2], a_nxt[4][2];
#pragma unroll
    for (int c = 0; c < 4; ++c)
      coh_issue2(lo + c * 4096 + s * 64 + tb * 8, a_cur[c][0], a_cur[c][1]);
    VMWAIT8(a_cur[0][0], a_cur[0][1], a_cur[1][0], a_cur[1][1], a_cur[2][0],
            a_cur[2][1], a_cur[3][0], a_cur[3][1]);
#pragma unroll
    for (int g = 0; g < 4; ++g) {
      if (g < 3) {
#pragma unroll
        for (int cc = 0; cc < 4; ++cc) {
          const int c = (g + 1) * 4 + cc;
          const float* p =
              (c < 8 ? lo + c * 4096 : hi + (c - 8) * 4096) + s * 64 + tb * 8;
          coh_issue2(p, a_nxt[cc][0], a_nxt[cc][1]);
        }
      }
      float4 wr[8];
#pragma unroll
      for (int r = 0; r < 8; ++r)
        wr[r] = *reinterpret_cast<const float4*>(
            &s_w[wbase + r * (64 * P) + g * 4]);
#pragma unroll
      for (int cc = 0; cc < 4; ++cc) {
        float av[8] = {a_cur[cc][0].x, a_cur[cc][0].y, a_cur[cc][0].z,
                       a_cur[cc][0].w, a_cur[cc][1].x, a_cur[cc][1].y,
                       a_cur[cc][1].z, a_cur[cc][1].w};
#pragma unroll
        for (int r = 0; r < 8; ++r) {
          float w = (cc == 0) ? wr[r].x
                  : (cc == 1) ? wr[r].y
                  : (cc == 2) ? wr[r].z
                              : wr[r].w;
#pragma unroll
          for (int bb = 0; bb < 8; ++bb)
            acc[r * 8 + bb] = fmaf(w, av[bb], acc[r * 8 + bb]);
        }
      }
      if (g < 3) {
        VMWAIT8(a_nxt[0][0], a_nxt[0][1], a_nxt[1][0], a_nxt[1][1],
                a_nxt[2][0], a_nxt[2][1], a_nxt[3][0], a_nxt[3][1]);
#pragma unroll
        for (int cc = 0; cc < 4; ++cc) {
          a_cur[cc][0] = a_nxt[cc][0];
          a_cur[cc][1] = a_nxt[cc][1];
        }
      }
    }

    // ---- exchange-and-halve reduction over lane bits 3..5 ----
    const int lane = tid & 63;
    const bool b3 = (lane & 8) != 0;
    const bool b4 = (lane & 16) != 0;
    const bool b5 = (lane & 32) != 0;
    float v32[32];
#pragma unroll
    for (int go = 0; go < 4; ++go)
#pragma unroll
      for (int j = 0; j < 8; ++j) {
        float lc = acc[(2 * go + 0) * 8 + j];
        float hc = acc[(2 * go + 1) * 8 + j];
        float lo_o = __shfl_xor(lc, 8, 64);
        float hi_o = __shfl_xor(hc, 8, 64);
        v32[go * 8 + j] = b3 ? (hc + hi_o) : (lc + lo_o);
      }
    float v16[16];
#pragma unroll
    for (int go = 0; go < 2; ++go)
#pragma unroll
      for (int j = 0; j < 8; ++j) {
        float lc = v32[(2 * go + 0) * 8 + j];
        float hc = v32[(2 * go + 1) * 8 + j];
        float lo_o = __shfl_xor(lc, 16, 64);
        float hi_o = __shfl_xor(hc, 16, 64);
        v16[go * 8 + j] = b4 ? (hc + hi_o) : (lc + lo_o);
      }
    float fin[8];
#pragma unroll
    for (int j = 0; j < 8; ++j) {
      float lc = v16[j];
      float hc = v16[8 + j];
      float lo_o = __shfl_xor(lc, 32, 64);
      float hi_o = __shfl_xor(hc, 32, 64);
      fin[j] = b5 ? (hc + hi_o) : (lc + lo_o);
    }
    const int wv = tid >> 6;
    const int sigma = (lane >> 3) & 7;
    float* dst = s_red + wv * 512 + sigma * 64 + tb * 8;
    *reinterpret_cast<float4*>(dst) = make_float4(fin[0], fin[1], fin[2], fin[3]);
    *reinterpret_cast<float4*>(dst + 4) =
        make_float4(fin[4], fin[5], fin[6], fin[7]);
    __syncthreads();
    {
      const float* bsum_l = ws + OFF_BSUM + layer * 4 * H;
      float sum = 0.f;
#pragma unroll
      for (int w8 = 0; w8 < 8; ++w8) sum += s_red[w8 * 512 + tid];
      int r = tid >> 6;
      int grow = (r >> 1) * 512 + wg * 2 + (r & 1);
      s_g[tid] = sum + bsum_l[grow];  // s_g[r*64+b]
    }
    __syncthreads();
  };

  float cs0 = 0.f, cs1 = 0.f;  // tid<128 owns (col=2wg+(tid>>6), b=tid&63)

  auto cell0_update = [&](float* dst) {
    if (tid < 128) {
      const int cc = tid >> 6, b = tid & 63, col = wg * 2 + cc;
      float ig = sigm(s_g[(0 + cc) * 64 + b]);
      float fg = sigm(s_g[(2 + cc) * 64 + b]);
      float gt = tanh_fast(s_g[(4 + cc) * 64 + b]);
      float og = sigm(s_g[(6 + cc) * 64 + b]);
      cs0 = fg * cs0 + ig * gt;
      coh_store1(dst + col * 64 + b, og * tanh_fast(cs0));
    }
  };
  auto cell1_update = [&](int p) {
    if (tid < 128) {
      const int cc = tid >> 6, b = tid & 63, col = wg * 2 + cc;
      float ig = sigm(s_g[(0 + cc) * 64 + b]);
      float fg = sigm(s_g[(2 + cc) * 64 + b]);
      float gt = tanh_fast(s_g[(4 + cc) * 64 + b]);
      float og = sigm(s_g[(6 + cc) * 64 + b]);
      cs1 = fg * cs1 + ig * gt;
      float h = og * tanh_fast(cs1);
      coh_store1(ws + OFF_H1 + p * HB + col * 64 + b, h);       // k-major
      coh_store1(ws + OFF_H1T + p * HB + b * 512 + col, h);     // b-major
    }
  };

  // ---------------- prologue ----------------
  inp_block(0, 0);
  inp_block(1, 1);
  gridbar();
  gemv(ws + OFF_INP + 0 * HB, ws + OFF_H0 + 1 * HB, 0);  // h0(-1)=par1 zeros
  cell0_update(ws + OFF_H0 + 0 * HB);
  gridbar();

  // ---------------- main loop: one barrier per step ----------------
  for (int t = 0; t < T_STEPS; ++t) {
    const int p = t & 1;
    gemv(ws + OFF_H0 + p * HB, ws + OFF_H1 + (1 - p) * HB, 1);
    cell1_update(p);
    if (t > 0) out_block(t - 1, 1 - p);
    if (t + 1 < T_STEPS) {
      gemv(ws + OFF_INP + (1 - p) * HB, ws + OFF_H0 + p * HB, 0);
      cell0_update(ws + OFF_H0 + (1 - p) * HB);
    }
    if (t + 2 < T_STEPS) inp_block(t + 2, p);
    gridbar();
  }
  out_block(T_STEPS - 1, 1);
}

extern "C" void kernel_launch(void* const* d_in, const int* in_sizes, int n_in,
                              void* d_out, int out_size, void* d_ws,
                              size_t ws_size, hipStream_t stream) {
  const float* x     = (const float*)d_in[0];
  const float* w_in  = (const float*)d_in[1];
  const float* b_in  = (const float*)d_in[2];
  const float* w_ih  = (const float*)d_in[3];
  const float* w_hh  = (const float*)d_in[4];
  const float* b_ih  = (const float*)d_in[5];
  const float* b_hh  = (const float*)d_in[6];
  const float* w_out = (const float*)d_in[7];
  const float* b_out = (const float*)d_in[8];
  float* ws   = (float*)d_ws;
  float* outp = (float*)d_out;

  hipLaunchKernelGGL(init_ws_kernel, dim3(NBLK), dim3(NTHR), 0, stream, ws,
                     b_ih, b_hh);
  hipLaunchKernelGGL(lstm_kernel, dim3(NBLK), dim3(NTHR), 0, stream, x, w_in,
                     b_in, w_ih, w_hh, w_out, b_out, ws, outp);
}